// Round 1
// baseline (296.542 us; speedup 1.0000x reference)
//
#include <hip/hip_runtime.h>
#include <hip/hip_bf16.h>

#define BATCH   16384
#define NUM_IN  4096
#define NUM_OUT 1024
#define NNZ     262144
#define BN_EPS  1e-3f

typedef __attribute__((ext_vector_type(8))) short   short8;   // 8 bf16 (4 VGPRs)
typedef __attribute__((ext_vector_type(4))) float   f32x4;
typedef __attribute__((ext_vector_type(4))) unsigned int u32x4;

__device__ inline unsigned short f2bf(float f) {
    // round-to-nearest-even fp32 -> bf16
    unsigned int u = __builtin_bit_cast(unsigned int, f);
    u += 0x7fffu + ((u >> 16) & 1u);
    return (unsigned short)(u >> 16);
}

// ---------------- kernel 1: zero W_t (fp32, transposed [NUM_OUT][NUM_IN]) ----
__global__ void k_zero(f32x4* __restrict__ p) {
    p[(size_t)blockIdx.x * 256 + threadIdx.x] = f32x4{0.f, 0.f, 0.f, 0.f};
}

// ---------------- kernel 2: scatter-add sparse values into W_t --------------
__global__ void k_scatter(const float* __restrict__ v, const int* __restrict__ r,
                          const int* __restrict__ c, float* __restrict__ wtf) {
    int i = blockIdx.x * 256 + threadIdx.x;
    // W[k=r][n=c] stored transposed: Wt[n][k]
    atomicAdd(&wtf[(size_t)c[i] * NUM_IN + r[i]], v[i]);
}

// ---------------- kernel 3: fold BN scale into W (bf16) + bias_out ----------
__global__ void k_wprep(const float* __restrict__ wtf, const float* __restrict__ gamma,
                        const float* __restrict__ beta, const float* __restrict__ mean,
                        const float* __restrict__ var, unsigned short* __restrict__ wtb,
                        float* __restrict__ bias) {
    const int n = blockIdx.x;
    const int t = threadIdx.x;
    float acc = 0.f;
    for (int k = t; k < NUM_IN; k += 256) {
        float w = wtf[(size_t)n * NUM_IN + k];
        float s = gamma[k] * rsqrtf(var[k] + BN_EPS);
        wtb[(size_t)n * NUM_IN + k] = f2bf(w * s);
        acc += (beta[k] - mean[k] * s) * w;
    }
    #pragma unroll
    for (int o = 32; o; o >>= 1) acc += __shfl_down(acc, o, 64);
    __shared__ float red[4];
    if ((t & 63) == 0) red[t >> 6] = acc;
    __syncthreads();
    if (t == 0) bias[n] = red[0] + red[1] + red[2] + red[3];
}

// ---------------- kernel 4: bf16 MFMA GEMM: out = x @ W'^T + bias -----------
// x: [BATCH][NUM_IN] fp32, wt: [NUM_OUT][NUM_IN] bf16 (i.e. W'^T, k-major)
// tile 128x128, BK=64, 256 threads = 4 waves (2x2), double-buffered LDS.
__global__ __launch_bounds__(256, 2) void k_gemm(const float* __restrict__ x,
                                                 const unsigned short* __restrict__ wt,
                                                 const float* __restrict__ bias,
                                                 float* __restrict__ out) {
    __shared__ char lds[65536];   // A0 A1 B0 B1, 16KB each

    // XCD-aware swizzle: consecutive logical tiles land on same XCD; the 8
    // n-tiles of one m-panel are consecutive -> A panel reuse hits that XCD's L2.
    const int bid = blockIdx.x;                 // 1024 blocks, 1024 % 8 == 0
    const int swz = (bid & 7) * 128 + (bid >> 3);
    const int m0 = (swz >> 3) * 128;
    const int n0 = (swz & 7) * 128;

    const int t    = threadIdx.x;
    const int lane = t & 63;
    const int w    = t >> 6;
    const int wm   = w >> 1;                    // 2x2 wave grid, 64x64 each
    const int wn   = w & 1;

    // staging decomposition: seg = 16B chunk (8 elems) in a 64-elem row
    const int seg = t & 7;
    const int r0  = t >> 3;                     // 0..31, rows r0 + 32*p

    f32x4 av[4][2];
    u32x4 bv[4];

    auto stage_load = [&](int kt) {
        const float* xa = x + (size_t)m0 * NUM_IN + kt * 64 + seg * 8;
        const unsigned short* wa = wt + (size_t)n0 * NUM_IN + kt * 64 + seg * 8;
        #pragma unroll
        for (int p = 0; p < 4; ++p) {
            int row = r0 + p * 32;
            const f32x4* s = (const f32x4*)(xa + (size_t)row * NUM_IN);
            av[p][0] = s[0];
            av[p][1] = s[1];
            bv[p] = *(const u32x4*)(wa + (size_t)row * NUM_IN);
        }
    };
    auto stage_write = [&](int buf) {
        char* A = lds + buf * 16384;
        char* B = lds + 32768 + buf * 16384;
        #pragma unroll
        for (int p = 0; p < 4; ++p) {
            int row = r0 + p * 32;
            int off = row * 128 + ((seg * 16) ^ ((row & 7) << 4));  // XOR swizzle
            short8 h;
            #pragma unroll
            for (int j = 0; j < 4; ++j) h[j] = (short)f2bf(av[p][0][j]);
            #pragma unroll
            for (int j = 0; j < 4; ++j) h[4 + j] = (short)f2bf(av[p][1][j]);
            *(short8*)(A + off) = h;
            *(u32x4*)(B + off) = bv[p];
        }
    };

    f32x4 acc[4][4] = {};

    auto compute = [&](int buf) {
        const char* A = lds + buf * 16384;
        const char* B = lds + 32768 + buf * 16384;
        #pragma unroll
        for (int kk = 0; kk < 2; ++kk) {
            const int koff = kk * 64 + ((lane >> 4) * 16);  // byte offset in 128B row
            short8 af[4], bfr[4];
            #pragma unroll
            for (int i = 0; i < 4; ++i) {
                int row = wm * 64 + i * 16 + (lane & 15);
                af[i] = *(const short8*)(A + row * 128 + (koff ^ ((row & 7) << 4)));
            }
            #pragma unroll
            for (int j = 0; j < 4; ++j) {
                int row = wn * 64 + j * 16 + (lane & 15);
                bfr[j] = *(const short8*)(B + row * 128 + (koff ^ ((row & 7) << 4)));
            }
            #pragma unroll
            for (int i = 0; i < 4; ++i)
                #pragma unroll
                for (int j = 0; j < 4; ++j)
                    acc[i][j] = __builtin_amdgcn_mfma_f32_16x16x32_bf16(
                        af[i], bfr[j], acc[i][j], 0, 0, 0);
        }
    };

    stage_load(0);
    stage_write(0);
    __syncthreads();

    const int NT = NUM_IN / 64;   // 64 K-steps
    for (int kt = 0; kt < NT; ++kt) {
        const int cur = kt & 1;
        if (kt + 1 < NT) stage_load(kt + 1);
        compute(cur);
        if (kt + 1 < NT) {
            stage_write(cur ^ 1);    // other buffer: safe vs. concurrent compute(cur)
            __syncthreads();
        }
    }

    // epilogue: D mapping col=lane&15, row=(lane>>4)*4+reg
    float bj[4];
    #pragma unroll
    for (int j = 0; j < 4; ++j) bj[j] = bias[n0 + wn * 64 + j * 16 + (lane & 15)];
    const int mbase = m0 + wm * 64 + (lane >> 4) * 4;
    const int nbase = n0 + wn * 64 + (lane & 15);
    #pragma unroll
    for (int i = 0; i < 4; ++i)
        #pragma unroll
        for (int j = 0; j < 4; ++j)
            #pragma unroll
            for (int r = 0; r < 4; ++r)
                out[(size_t)(mbase + i * 16 + r) * NUM_OUT + (nbase + j * 16)] =
                    acc[i][j][r] + bj[j];
}

extern "C" void kernel_launch(void* const* d_in, const int* in_sizes, int n_in,
                              void* d_out, int out_size, void* d_ws, size_t ws_size,
                              hipStream_t stream) {
    const float* x     = (const float*)d_in[0];
    const float* spv   = (const float*)d_in[1];
    const float* gamma = (const float*)d_in[2];
    const float* beta  = (const float*)d_in[3];
    const float* mean  = (const float*)d_in[4];
    const float* var   = (const float*)d_in[5];
    const int*   rows  = (const int*)d_in[6];
    const int*   cols  = (const int*)d_in[7];
    float* out = (float*)d_out;

    // W_t fp32 scratch lives in d_out (16 MB of the 64 MB output buffer; dead
    // before k_gemm overwrites all of d_out). ws holds Wt_bf16 (8 MB) + bias.
    float* wtf = (float*)d_out;
    unsigned short* wtb = (unsigned short*)d_ws;
    float* bias = (float*)((char*)d_ws + (size_t)NUM_IN * NUM_OUT * sizeof(unsigned short));

    hipLaunchKernelGGL(k_zero, dim3((NUM_IN * NUM_OUT / 4) / 256), dim3(256), 0, stream,
                       (f32x4*)wtf);
    hipLaunchKernelGGL(k_scatter, dim3(NNZ / 256), dim3(256), 0, stream,
                       spv, rows, cols, wtf);
    hipLaunchKernelGGL(k_wprep, dim3(NUM_OUT), dim3(256), 0, stream,
                       wtf, gamma, beta, mean, var, wtb, bias);
    hipLaunchKernelGGL(k_gemm, dim3((BATCH / 128) * (NUM_OUT / 128)), dim3(256), 0, stream,
                       x, wtb, bias, out);
}

// Round 2
// 226.244 us; speedup vs baseline: 1.3107x; 1.3107x over previous
//
#include <hip/hip_runtime.h>
#include <hip/hip_bf16.h>

#define BATCH   16384
#define NUM_IN  4096
#define NUM_OUT 1024
#define NNZ     262144
#define BN_EPS  1e-3f

typedef __attribute__((ext_vector_type(8))) short   short8;   // 8 bf16
typedef __attribute__((ext_vector_type(4))) float   f32x4;
typedef __attribute__((ext_vector_type(4))) unsigned int u32x4;

typedef __attribute__((address_space(3))) void        lds_void_t;
typedef const __attribute__((address_space(1))) void  g_void_t;

__device__ inline unsigned short f2bf(float f) {
    // round-to-nearest-even fp32 -> bf16 (used off the hot path)
    unsigned int u = __builtin_bit_cast(unsigned int, f);
    u += 0x7fffu + ((u >> 16) & 1u);
    return (unsigned short)(u >> 16);
}

// ---------------- kernel 1: zero W_t (fp32, transposed [NUM_OUT][NUM_IN]) ----
__global__ void k_zero(f32x4* __restrict__ p) {
    p[(size_t)blockIdx.x * 256 + threadIdx.x] = f32x4{0.f, 0.f, 0.f, 0.f};
}

// ---------------- kernel 2: scatter-add sparse values into W_t --------------
__global__ void k_scatter(const float* __restrict__ v, const int* __restrict__ r,
                          const int* __restrict__ c, float* __restrict__ wtf) {
    int i = blockIdx.x * 256 + threadIdx.x;
    atomicAdd(&wtf[(size_t)c[i] * NUM_IN + r[i]], v[i]);
}

// ---------------- kernel 3: fold BN scale into W (bf16) + bias_out ----------
__global__ void k_wprep(const float* __restrict__ wtf, const float* __restrict__ gamma,
                        const float* __restrict__ beta, const float* __restrict__ mean,
                        const float* __restrict__ var, unsigned short* __restrict__ wtb,
                        float* __restrict__ bias) {
    const int n = blockIdx.x;
    const int t = threadIdx.x;
    float acc = 0.f;
    for (int k = t; k < NUM_IN; k += 256) {
        float w = wtf[(size_t)n * NUM_IN + k];
        float s = gamma[k] * rsqrtf(var[k] + BN_EPS);
        wtb[(size_t)n * NUM_IN + k] = f2bf(w * s);
        acc += (beta[k] - mean[k] * s) * w;
    }
    #pragma unroll
    for (int o = 32; o; o >>= 1) acc += __shfl_down(acc, o, 64);
    __shared__ float red[4];
    if ((t & 63) == 0) red[t >> 6] = acc;
    __syncthreads();
    if (t == 0) bias[n] = red[0] + red[1] + red[2] + red[3];
}

// ---------------- kernel 4: bf16 MFMA GEMM: out = x @ W'^T + bias -----------
// BM=128, BN=256, BK=32. 512 thr = 8 waves (4M x 2N), per-wave 32x128.
// Ring-4 LDS buffers, all staging via global_load_lds (A fp32, B bf16),
// counted vmcnt(8) + raw s_barrier: loads span barriers (T3+T4).
#define BM 128
#define BN 256
#define BK 32
#define KTILES (NUM_IN / BK)   /* 128 */
#define ABUF 16384             /* 128 rows * 128 B (32 fp32) */
#define BBUF 16384             /* 256 rows *  64 B (32 bf16) */
#define LDS_B_OFF 65536

__global__ __launch_bounds__(512, 2) void k_gemm(const float* __restrict__ x,
                                                 const unsigned short* __restrict__ wt,
                                                 const float* __restrict__ bias,
                                                 float* __restrict__ out) {
    __shared__ __align__(128) char lds[131072];

    // XCD-aware swizzle: 512 blocks, 512%8==0 -> bijective. XCD x gets 64
    // consecutive logical tiles = 16 m-panels x their 4 n-siblings (A L2 reuse).
    const int bid = blockIdx.x;
    const int swz = (bid & 7) * 64 + (bid >> 3);
    const int m0 = (swz >> 2) * BM;
    const int n0 = (swz & 3) * BN;

    const int t    = threadIdx.x;
    const int lane = t & 63;
    const int wid  = t >> 6;
    const int wm   = wid >> 1;   // 0..3 -> 32-row strip
    const int wn   = wid & 1;    // 0..1 -> 128-col strip

    // staging decomposition (linear LDS dest, inverse-swizzled global source)
    const int arow0 = t >> 3;          // A: 8 thr/row (128 B), rows q*64 + arow0
    const int akb   = (t & 7) * 16;
    const int brow0 = t >> 2;          // B: 4 thr/row (64 B),  rows q*128 + brow0
    const int bkb   = (t & 3) * 16;

    const char* xb = (const char*)x;
    const char* wb = (const char*)wt;

    auto stage = [&](int kt) {
        const int buf = kt & 3;
        #pragma unroll
        for (int q = 0; q < 2; ++q) {        // A fp32: 2 x 8 KB
            int row = q * 64 + arow0;
            int src = (m0 + row) * (NUM_IN * 4) + kt * (BK * 4) + (akb ^ ((row & 7) << 4));
            __builtin_amdgcn_global_load_lds((g_void_t*)(xb + src),
                (lds_void_t*)(lds + buf * ABUF + q * 8192 + t * 16), 16, 0, 0);
        }
        #pragma unroll
        for (int q = 0; q < 2; ++q) {        // B bf16: 2 x 8 KB
            int row = q * 128 + brow0;
            int src = (n0 + row) * (NUM_IN * 2) + kt * (BK * 2) + (bkb ^ ((row & 3) << 4));
            __builtin_amdgcn_global_load_lds((g_void_t*)(wb + src),
                (lds_void_t*)(lds + LDS_B_OFF + buf * BBUF + q * 8192 + t * 16), 16, 0, 0);
        }
    };

    f32x4 acc[2][8] = {};

    const int arf = wm * 32 + (lane & 15);    // + m*16
    const int a_kb = (lane >> 4) * 32;        // 8 fp32 per lane
    const int brf = wn * 128 + (lane & 15);   // + j*16
    const int b_kb = (lane >> 4) * 16;        // 8 bf16 per lane

    auto compute = [&](int kt) {
        const char* A = lds + (kt & 3) * ABUF;
        const char* B = lds + LDS_B_OFF + (kt & 3) * BBUF;
        f32x4 ar[2][2];
        short8 bfr[8];
        #pragma unroll
        for (int m = 0; m < 2; ++m) {
            int row = arf + m * 16;
            int s = (row & 7) << 4;
            ar[m][0] = *(const f32x4*)(A + row * 128 + (a_kb ^ s));
            ar[m][1] = *(const f32x4*)(A + row * 128 + ((a_kb + 16) ^ s));
        }
        #pragma unroll
        for (int j = 0; j < 8; ++j) {
            int row = brf + j * 16;
            bfr[j] = *(const short8*)(B + row * 64 + (b_kb ^ ((row & 3) << 4)));
        }
        short8 af[2];
        #pragma unroll
        for (int m = 0; m < 2; ++m) {   // fp32 -> bf16 (RTZ) via v_perm, 1 op / 2 elems
            const unsigned int* f0 = (const unsigned int*)&ar[m][0];
            const unsigned int* f1 = (const unsigned int*)&ar[m][1];
            u32x4 p;
            p[0] = __builtin_amdgcn_perm(f0[1], f0[0], 0x07060302u);
            p[1] = __builtin_amdgcn_perm(f0[3], f0[2], 0x07060302u);
            p[2] = __builtin_amdgcn_perm(f1[1], f1[0], 0x07060302u);
            p[3] = __builtin_amdgcn_perm(f1[3], f1[2], 0x07060302u);
            af[m] = __builtin_bit_cast(short8, p);
        }
        __builtin_amdgcn_s_setprio(1);
        #pragma unroll
        for (int m = 0; m < 2; ++m)
            #pragma unroll
            for (int j = 0; j < 8; ++j)
                acc[m][j] = __builtin_amdgcn_mfma_f32_16x16x32_bf16(af[m], bfr[j],
                                                                    acc[m][j], 0, 0, 0);
        __builtin_amdgcn_s_setprio(0);
    };

    // prologue: fill 3 tiles ahead; wait tile 0 (12 outstanding -> allow 8)
    stage(0); stage(1); stage(2);
    asm volatile("s_waitcnt vmcnt(8)" ::: "memory");
    __builtin_amdgcn_s_barrier();
    __builtin_amdgcn_sched_barrier(0);

    for (int kt = 0; kt < KTILES - 3; ++kt) {      // 0..124
        stage(kt + 3);
        compute(kt);
        // outstanding: tiles kt+1..kt+3 (12) -> allow 8 => tile kt+1 landed
        asm volatile("s_waitcnt vmcnt(8)" ::: "memory");
        __builtin_amdgcn_s_barrier();
        __builtin_amdgcn_sched_barrier(0);
    }
    compute(KTILES - 3);                           // 125
    asm volatile("s_waitcnt vmcnt(4)" ::: "memory");
    __builtin_amdgcn_s_barrier();
    __builtin_amdgcn_sched_barrier(0);
    compute(KTILES - 2);                           // 126
    asm volatile("s_waitcnt vmcnt(0)" ::: "memory");
    __builtin_amdgcn_s_barrier();
    __builtin_amdgcn_sched_barrier(0);
    compute(KTILES - 1);                           // 127

    // epilogue: D frag mapping col=lane&15, row=(lane>>4)*4+r
    float bj[8];
    #pragma unroll
    for (int j = 0; j < 8; ++j) bj[j] = bias[n0 + wn * 128 + j * 16 + (lane & 15)];
    const int mb = m0 + wm * 32 + (lane >> 4) * 4;
    const int nb = n0 + wn * 128 + (lane & 15);
    #pragma unroll
    for (int m = 0; m < 2; ++m)
        #pragma unroll
        for (int j = 0; j < 8; ++j)
            #pragma unroll
            for (int r = 0; r < 4; ++r)
                out[(size_t)(mb + m * 16 + r) * NUM_OUT + (nb + j * 16)] =
                    acc[m][j][r] + bj[j];
}

extern "C" void kernel_launch(void* const* d_in, const int* in_sizes, int n_in,
                              void* d_out, int out_size, void* d_ws, size_t ws_size,
                              hipStream_t stream) {
    const float* x     = (const float*)d_in[0];
    const float* spv   = (const float*)d_in[1];
    const float* gamma = (const float*)d_in[2];
    const float* beta  = (const float*)d_in[3];
    const float* mean  = (const float*)d_in[4];
    const float* var   = (const float*)d_in[5];
    const int*   rows  = (const int*)d_in[6];
    const int*   cols  = (const int*)d_in[7];
    float* out = (float*)d_out;

    // W_t fp32 scratch lives in d_out (dead before k_gemm overwrites it).
    float* wtf = (float*)d_out;
    unsigned short* wtb = (unsigned short*)d_ws;
    float* bias = (float*)((char*)d_ws + (size_t)NUM_IN * NUM_OUT * sizeof(unsigned short));

    hipLaunchKernelGGL(k_zero, dim3((NUM_IN * NUM_OUT / 4) / 256), dim3(256), 0, stream,
                       (f32x4*)wtf);
    hipLaunchKernelGGL(k_scatter, dim3(NNZ / 256), dim3(256), 0, stream,
                       spv, rows, cols, wtf);
    hipLaunchKernelGGL(k_wprep, dim3(NUM_OUT), dim3(256), 0, stream,
                       wtf, gamma, beta, mean, var, wtb, bias);
    hipLaunchKernelGGL(k_gemm, dim3((BATCH / BM) * (NUM_OUT / BN)), dim3(512), 0, stream,
                       x, wtb, bias, out);
}

// Round 3
// 191.104 us; speedup vs baseline: 1.5517x; 1.1839x over previous
//
#include <hip/hip_runtime.h>
#include <hip/hip_bf16.h>

#define BATCH   16384
#define NUM_IN  4096
#define NUM_OUT 1024
#define NNZ     262144
#define BN_EPS  1e-3f

typedef __attribute__((ext_vector_type(8))) short   short8;   // 8 bf16
typedef __attribute__((ext_vector_type(4))) float   f32x4;
typedef __attribute__((ext_vector_type(4))) unsigned int u32x4;

typedef __attribute__((address_space(3))) void        lds_void_t;
typedef const __attribute__((address_space(1))) void  g_void_t;

__device__ inline unsigned short f2bf(float f) {
    // round-to-nearest-even fp32 -> bf16 (off the hot path)
    unsigned int u = __builtin_bit_cast(unsigned int, f);
    u += 0x7fffu + ((u >> 16) & 1u);
    return (unsigned short)(u >> 16);
}

// ---------------- kernel 1: zero W_t (fp32, transposed [NUM_OUT][NUM_IN]) ----
__global__ void k_zero(f32x4* __restrict__ p) {
    p[(size_t)blockIdx.x * 256 + threadIdx.x] = f32x4{0.f, 0.f, 0.f, 0.f};
}

// ---------------- kernel 2: scatter-add sparse values into W_t --------------
__global__ void k_scatter(const float* __restrict__ v, const int* __restrict__ r,
                          const int* __restrict__ c, float* __restrict__ wtf) {
    int i = blockIdx.x * 256 + threadIdx.x;
    atomicAdd(&wtf[(size_t)c[i] * NUM_IN + r[i]], v[i]);
}

// ---------------- kernel 3: fold BN scale into W (bf16) + bias_out ----------
__global__ void k_wprep(const float* __restrict__ wtf, const float* __restrict__ gamma,
                        const float* __restrict__ beta, const float* __restrict__ mean,
                        const float* __restrict__ var, unsigned short* __restrict__ wtb,
                        float* __restrict__ bias) {
    const int n = blockIdx.x;
    const int t = threadIdx.x;
    float acc = 0.f;
    for (int k = t; k < NUM_IN; k += 256) {
        float w = wtf[(size_t)n * NUM_IN + k];
        float s = gamma[k] * rsqrtf(var[k] + BN_EPS);
        wtb[(size_t)n * NUM_IN + k] = f2bf(w * s);
        acc += (beta[k] - mean[k] * s) * w;
    }
    #pragma unroll
    for (int o = 32; o; o >>= 1) acc += __shfl_down(acc, o, 64);
    __shared__ float red[4];
    if ((t & 63) == 0) red[t >> 6] = acc;
    __syncthreads();
    if (t == 0) bias[n] = red[0] + red[1] + red[2] + red[3];
}

// ---------------- kernel 4: bf16 MFMA GEMM: out = x @ W'^T + bias -----------
// BM=BN=256, BK=32. 512 thr = 8 waves (4M x 2N), per-wave 64x128.
// Ring-3 LDS (48 KB/tile: A fp32 32 KB + B bf16 16 KB), all staging via
// global_load_lds, counted vmcnt(6) + raw s_barrier (prefetch distance 2).
// Swizzles: A rows 128 B -> XOR (row&7)<<4; B rows 64 B -> XOR ((row>>1)&3)<<4
// (row parity supplies the half-select bit; covers all 8 bank regions, 2-way).
#define BM 256
#define BN 256
#define BK 32
#define KTILES (NUM_IN / BK)   /* 128 */
#define ABYTES 32768           /* 256 rows * 128 B (32 fp32) */
#define BBYTES 16384           /* 256 rows *  64 B (32 bf16) */
#define PBUF   49152

__global__ __launch_bounds__(512, 2) void k_gemm(const float* __restrict__ x,
                                                 const unsigned short* __restrict__ wt,
                                                 const float* __restrict__ bias,
                                                 float* __restrict__ out) {
    __shared__ __align__(128) char lds[3 * PBUF];   // 144 KB

    // XCD swizzle: 256 blocks (1/CU), 256%8==0 -> bijective. Each XCD gets 8
    // m-panels x all 4 n-tiles; x panel (4 MB) stays hot in that XCD's L2.
    const int bid = blockIdx.x;
    const int swz = (bid & 7) * 32 + (bid >> 3);
    const int m0 = (swz >> 2) * BM;
    const int n0 = (swz & 3) * BN;

    const int t    = threadIdx.x;
    const int lane = t & 63;
    const int wid  = t >> 6;
    const int wm   = wid >> 1;   // 0..3 -> 64-row strip
    const int wn   = wid & 1;    // 0..1 -> 128-col strip

    const char* xb = (const char*)x;
    const char* wb = (const char*)wt;

    // staging decomposition (linear LDS dest, inverse-swizzled global source)
    const int a_r0 = t >> 3, a_c = (t & 7) * 16;   // A: 8 thr/row (128 B)
    const int b_r0 = t >> 2, b_c = (t & 3) * 16;   // B: 4 thr/row (64 B)

    auto stage = [&](int kt, int buf) {
        char* base = lds + buf * PBUF;
        #pragma unroll
        for (int q = 0; q < 4; ++q) {              // A fp32: 4 x 8 KB
            int row = q * 64 + a_r0;
            size_t src = (size_t)(m0 + row) * (NUM_IN * 4) + kt * (BK * 4)
                       + (a_c ^ ((row & 7) << 4));
            __builtin_amdgcn_global_load_lds((g_void_t*)(xb + src),
                (lds_void_t*)(base + q * 8192 + t * 16), 16, 0, 0);
        }
        #pragma unroll
        for (int q = 0; q < 2; ++q) {              // B bf16: 2 x 8 KB
            int row = q * 128 + b_r0;
            size_t src = (size_t)(n0 + row) * (NUM_IN * 2) + kt * (BK * 2)
                       + (b_c ^ (((row >> 1) & 3) << 4));
            __builtin_amdgcn_global_load_lds((g_void_t*)(wb + src),
                (lds_void_t*)(base + ABYTES + q * 8192 + t * 16), 16, 0, 0);
        }
    };

    f32x4 acc[4][8] = {};

    const int a_row0 = wm * 64 + (lane & 15);      // + m*16
    const int a_kb   = (lane >> 4) * 32;           // 8 fp32 per lane (2 reads)
    const int b_row0 = wn * 128 + (lane & 15);     // + j*16
    const int b_kb   = (lane >> 4) * 16;           // 8 bf16 per lane

    auto compute = [&](int buf) {
        const char* A = lds + buf * PBUF;
        const char* B = A + ABYTES;
        short8 bfr[8];
        #pragma unroll
        for (int j = 0; j < 8; ++j) {
            int row = b_row0 + j * 16;
            bfr[j] = *(const short8*)(B + row * 64 + (b_kb ^ (((row >> 1) & 3) << 4)));
        }
        short8 af[4];
        #pragma unroll
        for (int m = 0; m < 4; ++m) {
            int row = a_row0 + m * 16;
            int s = (row & 7) << 4;
            f32x4 lo = *(const f32x4*)(A + row * 128 + (a_kb ^ s));
            f32x4 hi = *(const f32x4*)(A + row * 128 + ((a_kb + 16) ^ s));
            const unsigned int* f0 = (const unsigned int*)&lo;
            const unsigned int* f1 = (const unsigned int*)&hi;
            u32x4 p;   // fp32 -> bf16 (RTZ) via v_perm, 1 op / 2 elems
            p[0] = __builtin_amdgcn_perm(f0[1], f0[0], 0x07060302u);
            p[1] = __builtin_amdgcn_perm(f0[3], f0[2], 0x07060302u);
            p[2] = __builtin_amdgcn_perm(f1[1], f1[0], 0x07060302u);
            p[3] = __builtin_amdgcn_perm(f1[3], f1[2], 0x07060302u);
            af[m] = __builtin_bit_cast(short8, p);
        }
        __builtin_amdgcn_s_setprio(1);
        #pragma unroll
        for (int m = 0; m < 4; ++m)
            #pragma unroll
            for (int j = 0; j < 8; ++j)
                acc[m][j] = __builtin_amdgcn_mfma_f32_16x16x32_bf16(af[m], bfr[j],
                                                                    acc[m][j], 0, 0, 0);
        __builtin_amdgcn_s_setprio(0);
    };

    // prologue: fill tiles 0,1 (12 outstanding); wait tile 0 (allow 6)
    stage(0, 0);
    stage(1, 1);
    asm volatile("s_waitcnt vmcnt(6)" ::: "memory");
    __builtin_amdgcn_s_barrier();
    __builtin_amdgcn_sched_barrier(0);

    int cur = 0, sb = 2;
    for (int kt = 0; kt < KTILES - 2; ++kt) {      // kt = 0..125
        stage(kt + 2, sb);
        compute(cur);
        // outstanding: tiles kt+1 (6) + kt+2 (6) -> allow 6 => kt+1 landed
        asm volatile("s_waitcnt vmcnt(6)" ::: "memory");
        __builtin_amdgcn_s_barrier();
        __builtin_amdgcn_sched_barrier(0);
        cur = (cur == 2) ? 0 : cur + 1;
        sb  = (sb  == 2) ? 0 : sb  + 1;
    }
    compute(cur);                                  // kt = 126 (buf 0)
    cur = (cur == 2) ? 0 : cur + 1;
    asm volatile("s_waitcnt vmcnt(0)" ::: "memory");
    __builtin_amdgcn_s_barrier();
    __builtin_amdgcn_sched_barrier(0);
    compute(cur);                                  // kt = 127 (buf 1)

    // epilogue: D frag mapping col=lane&15, row=(lane>>4)*4+r
    float bj[8];
    #pragma unroll
    for (int j = 0; j < 8; ++j) bj[j] = bias[n0 + wn * 128 + j * 16 + (lane & 15)];
    const int mb = m0 + wm * 64 + (lane >> 4) * 4;
    const int nb = n0 + wn * 128 + (lane & 15);
    #pragma unroll
    for (int m = 0; m < 4; ++m)
        #pragma unroll
        for (int j = 0; j < 8; ++j)
            #pragma unroll
            for (int r = 0; r < 4; ++r)
                out[(size_t)(mb + m * 16 + r) * NUM_OUT + (nb + j * 16)] =
                    acc[m][j][r] + bj[j];
}

extern "C" void kernel_launch(void* const* d_in, const int* in_sizes, int n_in,
                              void* d_out, int out_size, void* d_ws, size_t ws_size,
                              hipStream_t stream) {
    const float* x     = (const float*)d_in[0];
    const float* spv   = (const float*)d_in[1];
    const float* gamma = (const float*)d_in[2];
    const float* beta  = (const float*)d_in[3];
    const float* mean  = (const float*)d_in[4];
    const float* var   = (const float*)d_in[5];
    const int*   rows  = (const int*)d_in[6];
    const int*   cols  = (const int*)d_in[7];
    float* out = (float*)d_out;

    // W_t fp32 scratch lives in d_out (dead before k_gemm overwrites it).
    float* wtf = (float*)d_out;
    unsigned short* wtb = (unsigned short*)d_ws;
    float* bias = (float*)((char*)d_ws + (size_t)NUM_IN * NUM_OUT * sizeof(unsigned short));

    hipLaunchKernelGGL(k_zero, dim3((NUM_IN * NUM_OUT / 4) / 256), dim3(256), 0, stream,
                       (f32x4*)wtf);
    hipLaunchKernelGGL(k_scatter, dim3(NNZ / 256), dim3(256), 0, stream,
                       spv, rows, cols, wtf);
    hipLaunchKernelGGL(k_wprep, dim3(NUM_OUT), dim3(256), 0, stream,
                       wtf, gamma, beta, mean, var, wtb, bias);
    hipLaunchKernelGGL(k_gemm, dim3((BATCH / BM) * (NUM_OUT / BN)), dim3(512), 0, stream,
                       x, wtb, bias, out);
}